// Round 6
// baseline (344.478 us; speedup 1.0000x reference)
//
#include <hip/hip_runtime.h>
#include <hip/hip_bf16.h>

#define D 128      // D_IN == D_OUT
#define SH 8       // log2 rows per bucket
#define BROWS 256  // rows per bucket
#define NBK_MAX 512
#define CH 8192    // edges per workgroup in k_pairs
#define CT 8       // col tiles (128/16)
#define KS 4       // k steps   (128/32)

typedef __bf16   bf16x8 __attribute__((ext_vector_type(8)));
typedef float    f32x4  __attribute__((ext_vector_type(4)));
typedef _Float16 f16x4  __attribute__((ext_vector_type(4)));
typedef _Float16 f16x8  __attribute__((ext_vector_type(8)));

// ===========================================================================
// CSR build (bucketed, proven round 5)
// ===========================================================================
__global__ __launch_bounds__(256) void k_zero(int* __restrict__ p, int n) {
    for (int i = blockIdx.x * blockDim.x + threadIdx.x; i < n; i += gridDim.x * blockDim.x)
        p[i] = 0;
}

__global__ __launch_bounds__(256) void k_bucket_count(const int* __restrict__ rows,
                                                      int* __restrict__ bcnt, int E, int NBK) {
    __shared__ int h[NBK_MAX];
    for (int i = threadIdx.x; i < NBK; i += 256) h[i] = 0;
    __syncthreads();
    for (int e = blockIdx.x * blockDim.x + threadIdx.x; e < E; e += gridDim.x * blockDim.x)
        atomicAdd(&h[rows[e] >> SH], 1);
    __syncthreads();
    for (int i = threadIdx.x; i < NBK; i += 256) {
        int v = h[i];
        if (v) atomicAdd(&bcnt[i], v);
    }
}

__global__ __launch_bounds__(512) void k_scan_buckets(const int* __restrict__ bcnt,
                                                      int* __restrict__ boff,
                                                      int* __restrict__ bcur, int NBK, int E) {
    __shared__ int sd[512];
    int t = threadIdx.x;
    int own = (t < NBK) ? bcnt[t] : 0;
    sd[t] = own;
    __syncthreads();
    for (int off = 1; off < 512; off <<= 1) {
        int add = (t >= off) ? sd[t - off] : 0;
        __syncthreads();
        sd[t] += add;
        __syncthreads();
    }
    if (t < NBK) {
        int ex = sd[t] - own;
        boff[t] = ex;
        bcur[t] = ex;
    }
    if (t == 0) boff[NBK] = E;
}

__global__ __launch_bounds__(256) void k_pairs(const int* __restrict__ rows,
                                               const int* __restrict__ cols,
                                               int* __restrict__ bcur,
                                               unsigned* __restrict__ pairs, int E, int NBK) {
    __shared__ int h[NBK_MAX];
    int e0 = blockIdx.x * CH;
    if (e0 >= E) return;
    int e1 = min(E, e0 + CH);
    for (int i = threadIdx.x; i < NBK; i += 256) h[i] = 0;
    __syncthreads();
    for (int e = e0 + threadIdx.x; e < e1; e += 256)
        atomicAdd(&h[rows[e] >> SH], 1);
    __syncthreads();
    for (int b = threadIdx.x; b < NBK; b += 256) {
        int v = h[b];
        h[b] = v ? atomicAdd(&bcur[b], v) : 0;
    }
    __syncthreads();
    for (int e = e0 + threadIdx.x; e < e1; e += 256) {
        int r = rows[e];
        int b = r >> SH;
        int p = atomicAdd(&h[b], 1);
        pairs[p] = ((unsigned)(r & (BROWS - 1)) << 24) | (unsigned)cols[e];
    }
}

__global__ __launch_bounds__(256) void k_bucket_hist(const unsigned* __restrict__ pairs,
                                                     const int* __restrict__ boff,
                                                     int* __restrict__ cnt, int N) {
    __shared__ int h[BROWS];
    int b = blockIdx.x;
    int lim = min(N - (b << SH), BROWS);
    h[threadIdx.x] = 0;
    __syncthreads();
    int p0 = boff[b], p1 = boff[b + 1];
    for (int p = p0 + threadIdx.x; p < p1; p += 256)
        atomicAdd(&h[pairs[p] >> 24], 1);
    __syncthreads();
    if (threadIdx.x < lim) cnt[(b << SH) + threadIdx.x] = h[threadIdx.x];
}

__global__ __launch_bounds__(256) void k_chunk_sum(const int* __restrict__ cnt,
                                                   int* __restrict__ bsum, int N) {
    __shared__ int sd[256];
    int base = blockIdx.x * 1024;
    int t = threadIdx.x;
    int s = 0;
#pragma unroll
    for (int k = 0; k < 4; ++k) {
        int i = base + t * 4 + k;
        if (i < N) s += cnt[i];
    }
    sd[t] = s;
    __syncthreads();
    for (int off = 128; off > 0; off >>= 1) {
        if (t < off) sd[t] += sd[t + off];
        __syncthreads();
    }
    if (t == 0) bsum[blockIdx.x] = sd[0];
}

__global__ __launch_bounds__(1024) void k_scan_tops(const int* __restrict__ bsum,
                                                    int* __restrict__ boff2, int nb,
                                                    int* __restrict__ row_start, int N, int E) {
    __shared__ int sd[1024];
    int t = threadIdx.x;
    int own = (t < nb) ? bsum[t] : 0;
    sd[t] = own;
    __syncthreads();
    for (int off = 1; off < 1024; off <<= 1) {
        int add = (t >= off) ? sd[t - off] : 0;
        __syncthreads();
        sd[t] += add;
        __syncthreads();
    }
    if (t < nb) boff2[t] = sd[t] - own;
    if (t == 0) row_start[N] = E;
}

__global__ __launch_bounds__(256) void k_scan_chunk(const int* __restrict__ cnt,
                                                    const int* __restrict__ boff2,
                                                    int* __restrict__ row_start,
                                                    float* __restrict__ dr, int N) {
    __shared__ int tsum[256];
    int base = blockIdx.x * 1024;
    int t = threadIdx.x;
    int v[4];
    int s = 0;
#pragma unroll
    for (int k = 0; k < 4; ++k) {
        int i = base + t * 4 + k;
        v[k] = (i < N) ? cnt[i] : 0;
        s += v[k];
    }
    tsum[t] = s;
    __syncthreads();
    for (int off = 1; off < 256; off <<= 1) {
        int add = (t >= off) ? tsum[t - off] : 0;
        __syncthreads();
        tsum[t] += add;
        __syncthreads();
    }
    int run = boff2[blockIdx.x] + tsum[t] - s;
#pragma unroll
    for (int k = 0; k < 4; ++k) {
        int i = base + t * 4 + k;
        if (i < N) {
            row_start[i] = run;
            dr[i] = rsqrtf((float)(v[k] + 1));
            run += v[k];
        }
    }
}

__global__ __launch_bounds__(256) void k_place(const unsigned* __restrict__ pairs,
                                               const int* __restrict__ boff,
                                               const int* __restrict__ row_start,
                                               int* __restrict__ csr_col, int N) {
    __shared__ int cur[BROWS];
    int b = blockIdx.x;
    int lim = min(N - (b << SH), BROWS);
    if (threadIdx.x < lim) cur[threadIdx.x] = row_start[(b << SH) + threadIdx.x];
    __syncthreads();
    int p0 = boff[b], p1 = boff[b + 1];
    for (int p = p0 + threadIdx.x; p < p1; p += 256) {
        unsigned v = pairs[p];
        int rl = v >> 24;
        int c  = v & 0xFFFFFF;
        int q = atomicAdd(&cur[rl], 1);
        csr_col[q] = c;
    }
}

// x (fp32) -> xh (fp16), pre-scaled by dr: xh[i][:] = dr[i] * x[i][:]
__global__ __launch_bounds__(256) void k_half_s(const float4* __restrict__ x4,
                                                const float* __restrict__ dr,
                                                f16x4* __restrict__ xh4, int n4) {
    for (int i = blockIdx.x * blockDim.x + threadIdx.x; i < n4; i += gridDim.x * blockDim.x) {
        float d = dr[i >> 5];   // 32 float4 per row
        float4 v = x4[i];
        xh4[i] = (f16x4){(_Float16)(v.x * d), (_Float16)(v.y * d),
                         (_Float16)(v.z * d), (_Float16)(v.w * d)};
    }
}

// pre-pack W fragments (bf16 hi/lo split) in MFMA fragment order into global ws
__global__ __launch_bounds__(256) void k_prepW(const float* __restrict__ W,
                                               bf16x8* __restrict__ Whi,
                                               bf16x8* __restrict__ Wlo) {
    for (int f = blockIdx.x * blockDim.x + threadIdx.x; f < CT * KS * 64;
         f += gridDim.x * blockDim.x) {
        int l  = f & 63;
        int ks = (f >> 6) & 3;
        int ct = f >> 8;
        int o  = ct * 16 + (l & 15);
        int k0 = ks * 32 + ((l >> 4) * 8);
        const float* src = &W[o * D + k0];
        bf16x8 hi, lo;
#pragma unroll
        for (int i = 0; i < 8; ++i) {
            float v  = src[i];
            __bf16 h = (__bf16)v;
            hi[i] = h;
            lo[i] = (__bf16)(v - (float)h);
        }
        Whi[f] = hi;
        Wlo[f] = lo;
    }
}

// ===========================================================================
// fused gather + projection + relu.
// One wave per 16-row tile. Gather phase: lane l covers d-chunk (l&15)*8..+7
// of edge-slot (l>>4) -> 4 edges per f16x8 load instruction (1 KB/instr).
// Cross-slot combine via shfl_xor(16/32); drr applied once per row.
// A-frags staged via wave-private LDS patch; 96 MFMAs vs pre-packed W frags.
// ===========================================================================
__global__ __launch_bounds__(256) void k_gp(const int* __restrict__ row_start,
                                            const int* __restrict__ csr_col,
                                            const _Float16* __restrict__ xh,
                                            const float* __restrict__ dr,
                                            const bf16x8* __restrict__ Whi,
                                            const bf16x8* __restrict__ Wlo,
                                            float* __restrict__ out, int NT) {
    __shared__ float lds[4][16][132];
    int lane = threadIdx.x & 63;
    int wib  = threadIdx.x >> 6;
    float (*patch)[132] = lds[wib];

    int gw = (blockIdx.x * blockDim.x + threadIdx.x) >> 6;
    int nw = (gridDim.x * blockDim.x) >> 6;

    int eslot = lane >> 4;          // edge slot 0..3
    int dbase = (lane & 15) * 8;    // d-chunk base

    for (int t = gw; t < NT; t += nw) {
        int r0 = t * 16;
        // tile-wide prefetch of row_start / dr
        int   rs16 = (lane < 17) ? row_start[r0 + lane] : 0;
        float dr16 = (lane < 16) ? dr[r0 + lane] : 0.f;

        for (int rr = 0; rr < 16; ++rr) {
            int r   = r0 + rr;
            int beg = __shfl(rs16, rr);
            int end = __shfl(rs16, rr + 1);
            float drr = __shfl(dr16, rr);

            // self term: xh'[r] (eslot 0 only, to avoid 4x counting in reduce)
            float acc[8];
            {
                f16x8 xs = *(const f16x8*)&xh[(size_t)r * D + dbase];
                float w = (eslot == 0) ? 1.0f : 0.0f;
#pragma unroll
                for (int i = 0; i < 8; ++i) acc[i] = w * (float)xs[i];
            }

            for (int cb = beg; cb < end; cb += 64) {
                int m = end - cb;
                if (m > 64) m = 64;
                int cidx = (lane < m) ? csr_col[cb + lane] : 0;
                int g = 0;
                // main: 16 edges per iter, 4 loads in flight, no masking
                for (; g + 16 <= m; g += 16) {
                    int c0 = __shfl(cidx, g + eslot);
                    int c1 = __shfl(cidx, g + 4 + eslot);
                    int c2 = __shfl(cidx, g + 8 + eslot);
                    int c3 = __shfl(cidx, g + 12 + eslot);
                    f16x8 p0 = *(const f16x8*)&xh[(size_t)c0 * D + dbase];
                    f16x8 p1 = *(const f16x8*)&xh[(size_t)c1 * D + dbase];
                    f16x8 p2 = *(const f16x8*)&xh[(size_t)c2 * D + dbase];
                    f16x8 p3 = *(const f16x8*)&xh[(size_t)c3 * D + dbase];
#pragma unroll
                    for (int i = 0; i < 8; ++i) {
                        acc[i] += (float)p0[i] + (float)p1[i];
                        acc[i] += (float)p2[i] + (float)p3[i];
                    }
                }
                // remainder: groups of 4 with masking
                for (; g < m; g += 4) {
                    int src = g + eslot;
                    bool valid = (src < m);
                    int c = __shfl(cidx, valid ? src : 0);
                    int cc = valid ? c : r;   // harmless (L1-hot) load
                    f16x8 pv = *(const f16x8*)&xh[(size_t)cc * D + dbase];
                    float w = valid ? 1.0f : 0.0f;
#pragma unroll
                    for (int i = 0; i < 8; ++i) acc[i] = fmaf(w, (float)pv[i], acc[i]);
                }
            }

            // combine edge slots; apply drr once
#pragma unroll
            for (int i = 0; i < 8; ++i) {
                acc[i] += __shfl_xor(acc[i], 16);
                acc[i] += __shfl_xor(acc[i], 32);
                acc[i] *= drr;
            }
            if (lane < 16) {
                *(float4*)&patch[rr][dbase]     = make_float4(acc[0], acc[1], acc[2], acc[3]);
                *(float4*)&patch[rr][dbase + 4] = make_float4(acc[4], acc[5], acc[6], acc[7]);
            }
        }

        // ---- projection (wave-private patch; no barrier needed) ----
        int arow  = lane & 15;
        int kbase = (lane >> 4) * 8;
        bf16x8 Ahi[KS], Alo[KS];
#pragma unroll
        for (int ks = 0; ks < KS; ++ks) {
            int k0 = ks * 32 + kbase;
            float4 v0 = *(const float4*)&patch[arow][k0];
            float4 v1 = *(const float4*)&patch[arow][k0 + 4];
            float va[8] = {v0.x, v0.y, v0.z, v0.w, v1.x, v1.y, v1.z, v1.w};
            bf16x8 hi, lo;
#pragma unroll
            for (int i = 0; i < 8; ++i) {
                __bf16 h = (__bf16)va[i];
                hi[i] = h;
                lo[i] = (__bf16)(va[i] - (float)h);
            }
            Ahi[ks] = hi;
            Alo[ks] = lo;
        }

        f32x4 acc4[CT];
#pragma unroll
        for (int ct = 0; ct < CT; ++ct) acc4[ct] = (f32x4){0.f, 0.f, 0.f, 0.f};
#pragma unroll
        for (int ks = 0; ks < KS; ++ks) {
#pragma unroll
            for (int ct = 0; ct < CT; ++ct) {
                bf16x8 bh = Whi[(ct * KS + ks) * 64 + lane];
                bf16x8 bl = Wlo[(ct * KS + ks) * 64 + lane];
                acc4[ct] = __builtin_amdgcn_mfma_f32_16x16x32_bf16(Ahi[ks], bh, acc4[ct], 0, 0, 0);
                acc4[ct] = __builtin_amdgcn_mfma_f32_16x16x32_bf16(Alo[ks], bh, acc4[ct], 0, 0, 0);
                acc4[ct] = __builtin_amdgcn_mfma_f32_16x16x32_bf16(Ahi[ks], bl, acc4[ct], 0, 0, 0);
            }
        }

        int orow = r0 + (lane >> 4) * 4;
        int ocol = lane & 15;
#pragma unroll
        for (int ct = 0; ct < CT; ++ct) {
#pragma unroll
            for (int reg = 0; reg < 4; ++reg) {
                out[(size_t)(orow + reg) * D + ct * 16 + ocol] = fmaxf(acc4[ct][reg], 0.f);
            }
        }
    }
}

// ===========================================================================
// mid-tier fallback: fp32 gather + standalone MFMA project (proven round 3/5)
// ===========================================================================
__global__ __launch_bounds__(256) void k_gather(const int* __restrict__ row_start,
                                                const int* __restrict__ csr_col,
                                                const float* __restrict__ x,
                                                const float* __restrict__ dr,
                                                float* __restrict__ out, int N) {
    int lane = threadIdx.x & 63;
    int gw = (blockIdx.x * blockDim.x + threadIdx.x) >> 6;
    int nw = (gridDim.x * blockDim.x) >> 6;
    for (int r = gw; r < N; r += nw) {
        float drr = dr[r];
        int beg = row_start[r], end = row_start[r + 1];
        const float2 xs = *(const float2*)&x[(size_t)r * D + lane * 2];
        float s = drr * drr;
        float a0 = s * xs.x, a1 = s * xs.y;
        for (int cb = beg; cb < end; cb += 64) {
            int m = end - cb;
            if (m > 64) m = 64;
            int   cidx = (lane < m) ? csr_col[cb + lane] : 0;
            float cdr  = (lane < m) ? dr[cidx] : 0.f;
            int j = 0;
            for (; j + 4 <= m; j += 4) {
                int c0 = __shfl(cidx, j);
                int c1 = __shfl(cidx, j + 1);
                int c2 = __shfl(cidx, j + 2);
                int c3 = __shfl(cidx, j + 3);
                float v0 = drr * __shfl(cdr, j);
                float v1 = drr * __shfl(cdr, j + 1);
                float v2 = drr * __shfl(cdr, j + 2);
                float v3 = drr * __shfl(cdr, j + 3);
                const float2 p0 = *(const float2*)&x[(size_t)c0 * D + lane * 2];
                const float2 p1 = *(const float2*)&x[(size_t)c1 * D + lane * 2];
                const float2 p2 = *(const float2*)&x[(size_t)c2 * D + lane * 2];
                const float2 p3 = *(const float2*)&x[(size_t)c3 * D + lane * 2];
                a0 = fmaf(v0, p0.x, a0); a1 = fmaf(v0, p0.y, a1);
                a0 = fmaf(v1, p1.x, a0); a1 = fmaf(v1, p1.y, a1);
                a0 = fmaf(v2, p2.x, a0); a1 = fmaf(v2, p2.y, a1);
                a0 = fmaf(v3, p3.x, a0); a1 = fmaf(v3, p3.y, a1);
            }
            for (; j < m; ++j) {
                int   c = __shfl(cidx, j);
                float v = drr * __shfl(cdr, j);
                const float2 p = *(const float2*)&x[(size_t)c * D + lane * 2];
                a0 = fmaf(v, p.x, a0);
                a1 = fmaf(v, p.y, a1);
            }
        }
        float2 o;
        o.x = a0;
        o.y = a1;
        *(float2*)&out[(size_t)r * D + lane * 2] = o;
    }
}

__global__ __launch_bounds__(256) void k_project_mfma(const float* __restrict__ W,
                                                      float* __restrict__ out, int N) {
    __shared__ bf16x8 Bhi[CT * KS * 64];
    __shared__ bf16x8 Blo[CT * KS * 64];
    for (int f = threadIdx.x; f < CT * KS * 64; f += 256) {
        int l  = f & 63;
        int ks = (f >> 6) & 3;
        int ct = f >> 8;
        int o  = ct * 16 + (l & 15);
        int k0 = ks * 32 + ((l >> 4) * 8);
        const float* src = &W[o * D + k0];
        bf16x8 hi, lo;
#pragma unroll
        for (int i = 0; i < 8; ++i) {
            float v  = src[i];
            __bf16 h = (__bf16)v;
            hi[i] = h;
            lo[i] = (__bf16)(v - (float)h);
        }
        Bhi[f] = hi;
        Blo[f] = lo;
    }
    __syncthreads();

    int lane = threadIdx.x & 63;
    int wib  = threadIdx.x >> 6;
    int gw   = blockIdx.x * 4 + wib;
    int nw   = gridDim.x * 4;
    int nt   = N >> 4;
    int arow  = lane & 15;
    int kbase = (lane >> 4) * 8;

    for (int t = gw; t < nt; t += nw) {
        int row = t * 16 + arow;
        const float* arp = &out[(size_t)row * D + kbase];
        bf16x8 Ahi[KS], Alo[KS];
#pragma unroll
        for (int ks = 0; ks < KS; ++ks) {
            float4 v0 = *(const float4*)&arp[ks * 32];
            float4 v1 = *(const float4*)&arp[ks * 32 + 4];
            float va[8] = {v0.x, v0.y, v0.z, v0.w, v1.x, v1.y, v1.z, v1.w};
            bf16x8 hi, lo;
#pragma unroll
            for (int i = 0; i < 8; ++i) {
                __bf16 h = (__bf16)va[i];
                hi[i] = h;
                lo[i] = (__bf16)(va[i] - (float)h);
            }
            Ahi[ks] = hi;
            Alo[ks] = lo;
        }
        f32x4 acc[CT];
#pragma unroll
        for (int ct = 0; ct < CT; ++ct) acc[ct] = (f32x4){0.f, 0.f, 0.f, 0.f};
#pragma unroll
        for (int ks = 0; ks < KS; ++ks) {
#pragma unroll
            for (int ct = 0; ct < CT; ++ct) {
                bf16x8 bh = Bhi[(ct * KS + ks) * 64 + lane];
                bf16x8 bl = Blo[(ct * KS + ks) * 64 + lane];
                acc[ct] = __builtin_amdgcn_mfma_f32_16x16x32_bf16(Ahi[ks], bh, acc[ct], 0, 0, 0);
                acc[ct] = __builtin_amdgcn_mfma_f32_16x16x32_bf16(Alo[ks], bh, acc[ct], 0, 0, 0);
                acc[ct] = __builtin_amdgcn_mfma_f32_16x16x32_bf16(Ahi[ks], bl, acc[ct], 0, 0, 0);
            }
        }
        int orow = t * 16 + (lane >> 4) * 4;
        int ocol = lane & 15;
#pragma unroll
        for (int ct = 0; ct < CT; ++ct) {
#pragma unroll
            for (int reg = 0; reg < 4; ++reg) {
                out[(size_t)(orow + reg) * D + ct * 16 + ocol] = fmaxf(acc[ct][reg], 0.f);
            }
        }
    }
}

// ===========================================================================
// last-resort fallback (atomic path)
// ===========================================================================
__global__ __launch_bounds__(256) void k_init_deg(int* __restrict__ deg, int n) {
    for (int i = blockIdx.x * blockDim.x + threadIdx.x; i < n; i += gridDim.x * blockDim.x)
        deg[i] = 1;
}
__global__ __launch_bounds__(256) void k_count_atomic(const int* __restrict__ rows,
                                                      int* __restrict__ cnt, int E) {
    for (int e = blockIdx.x * blockDim.x + threadIdx.x; e < E; e += gridDim.x * blockDim.x)
        atomicAdd(&cnt[rows[e]], 1);
}
__global__ __launch_bounds__(256) void k_rsqrt(float* __restrict__ buf, int n) {
    const int* di = (const int*)buf;
    for (int i = blockIdx.x * blockDim.x + threadIdx.x; i < n; i += gridDim.x * blockDim.x) {
        int v = di[i];
        buf[i] = rsqrtf((float)v);
    }
}
__global__ __launch_bounds__(256) void k_init_out(const float4* __restrict__ x4,
                                                  const float* __restrict__ dr,
                                                  float4* __restrict__ out4, int n4) {
    for (int i = blockIdx.x * blockDim.x + threadIdx.x; i < n4; i += gridDim.x * blockDim.x) {
        float d = dr[i >> 5];
        float s = d * d;
        float4 v = x4[i];
        out4[i] = make_float4(v.x * s, v.y * s, v.z * s, v.w * s);
    }
}
__global__ __launch_bounds__(256) void k_edges(const int* __restrict__ rows,
                                               const int* __restrict__ cols,
                                               const float* __restrict__ x,
                                               const float* __restrict__ dr,
                                               float* __restrict__ out, int E) {
    int lane = threadIdx.x & 63;
    int wib  = threadIdx.x >> 6;
    int gw   = blockIdx.x * 4 + wib;
    int nw   = gridDim.x * 4;
    for (int e = gw; e < E; e += nw) {
        int r = rows[e];
        int c = cols[e];
        float val = dr[r] * dr[c];
        const float2 xv = *(const float2*)&x[(size_t)c * D + lane * 2];
        float* po = &out[(size_t)r * D + lane * 2];
        unsafeAtomicAdd(po,     val * xv.x);
        unsafeAtomicAdd(po + 1, val * xv.y);
    }
}

// ===========================================================================
extern "C" void kernel_launch(void* const* d_in, const int* in_sizes, int n_in,
                              void* d_out, int out_size, void* d_ws, size_t ws_size,
                              hipStream_t stream) {
    const float* x   = (const float*)d_in[0];
    const int*   idx = (const int*)d_in[1];
    const float* W   = (const float*)d_in[2];
    float*       out = (float*)d_out;

    int N = in_sizes[0] / D;   // 100000
    int E = in_sizes[1] / 2;   // 1.6M
    const int* rows = idx;
    const int* cols = idx + E;

    int NBK = (N + BROWS - 1) >> SH;   // 391
    int nb  = (N + 1023) / 1024;       // 98

    // workspace layout in 4B words
    size_t off = 0;
    size_t o_pairs = off;  off += (size_t)E;
    size_t o_csr   = off;  off += (size_t)E;
    size_t o_cnt   = off;  off += (size_t)N;
    size_t o_rs    = off;  off += (size_t)N + 1;
    size_t o_dr    = off;  off += (size_t)N;
    size_t o_bsum  = off;  off += (size_t)nb;
    size_t o_boff2 = off;  off += (size_t)nb;
    size_t o_bcnt  = off;  off += (size_t)NBK;
    size_t o_boff  = off;  off += (size_t)NBK + 1;
    size_t o_bcur  = off;  off += (size_t)NBK;
    off = (off + 3) & ~(size_t)3;      // 16B align
    size_t need_mid = off * 4;         // mid-tier path end
    size_t o_whi   = off;  off += (size_t)(CT * KS * 64) * 4;   // bf16x8 = 4 words
    size_t o_wlo   = off;  off += (size_t)(CT * KS * 64) * 4;
    size_t o_xh    = off;  off += ((size_t)N * D) / 2;          // halves = words/2
    size_t need_full = off * 4;

    int* wsw = (int*)d_ws;
    bool shape_ok = (NBK <= NBK_MAX) && (nb <= 1024) && ((N & 15) == 0) && (N < (1 << 24));

    if (shape_ok && ws_size >= need_mid) {
        unsigned* pairs     = (unsigned*)(wsw + o_pairs);
        int*      csr_col   = wsw + o_csr;
        int*      cnt       = wsw + o_cnt;
        int*      row_start = wsw + o_rs;
        float*    dr        = (float*)(wsw + o_dr);
        int*      bsum      = wsw + o_bsum;
        int*      boff2     = wsw + o_boff2;
        int*      bcnt      = wsw + o_bcnt;
        int*      boff      = wsw + o_boff;
        int*      bcur      = wsw + o_bcur;

        // CSR build (bucketed)
        k_zero<<<(NBK + 255) / 256, 256, 0, stream>>>(bcnt, NBK);
        k_bucket_count<<<512, 256, 0, stream>>>(rows, bcnt, E, NBK);
        k_scan_buckets<<<1, 512, 0, stream>>>(bcnt, boff, bcur, NBK, E);
        k_pairs<<<(E + CH - 1) / CH, 256, 0, stream>>>(rows, cols, bcur, pairs, E, NBK);
        k_bucket_hist<<<NBK, 256, 0, stream>>>(pairs, boff, cnt, N);
        k_chunk_sum<<<nb, 256, 0, stream>>>(cnt, bsum, N);
        k_scan_tops<<<1, 1024, 0, stream>>>(bsum, boff2, nb, row_start, N, E);
        k_scan_chunk<<<nb, 256, 0, stream>>>(cnt, boff2, row_start, dr, N);
        k_place<<<NBK, 256, 0, stream>>>(pairs, boff, row_start, csr_col, N);

        if (ws_size >= need_full) {
            bf16x8*   Whi = (bf16x8*)(wsw + o_whi);
            bf16x8*   Wlo = (bf16x8*)(wsw + o_wlo);
            _Float16* xh  = (_Float16*)(wsw + o_xh);
            k_prepW<<<8, 256, 0, stream>>>(W, Whi, Wlo);
            k_half_s<<<2048, 256, 0, stream>>>((const float4*)x, dr, (f16x4*)xh, N * (D / 4));
            int NT = N >> 4;
            k_gp<<<(NT + 3) / 4, 256, 0, stream>>>(row_start, csr_col, xh, dr, Whi, Wlo, out, NT);
        } else {
            k_gather<<<4096, 256, 0, stream>>>(row_start, csr_col, x, dr, out, N);
            int nt = N >> 4;
            k_project_mfma<<<(nt + 3) / 4, 256, 0, stream>>>(W, out, N);
        }
    } else {
        int*   deg = (int*)d_ws;
        float* dr  = (float*)d_ws;
        k_init_deg<<<(N + 255) / 256, 256, 0, stream>>>(deg, N);
        k_count_atomic<<<2048, 256, 0, stream>>>(rows, deg, E);
        k_rsqrt<<<(N + 255) / 256, 256, 0, stream>>>(dr, N);
        int n4 = N * (D / 4);
        k_init_out<<<4096, 256, 0, stream>>>((const float4*)x, dr, (float4*)out, n4);
        k_edges<<<4096, 256, 0, stream>>>(rows, cols, x, dr, out, E);
        int nt = N >> 4;
        k_project_mfma<<<(nt + 3) / 4, 256, 0, stream>>>(W, out, N);
    }
}

// Round 7
// 219.229 us; speedup vs baseline: 1.5713x; 1.5713x over previous
//
#include <hip/hip_runtime.h>
#include <hip/hip_bf16.h>

#define D 128      // D_IN == D_OUT
#define SH 8       // log2 rows per bucket
#define BROWS 256  // rows per bucket
#define NBK_MAX 512
#define CH 8192    // edges per workgroup in k_pairs
#define CT 8       // col tiles (128/16)
#define KS 4       // k steps   (128/32)

typedef __bf16   bf16x8 __attribute__((ext_vector_type(8)));
typedef float    f32x4  __attribute__((ext_vector_type(4)));
typedef _Float16 f16x2  __attribute__((ext_vector_type(2)));
typedef _Float16 f16x4  __attribute__((ext_vector_type(4)));

// ===========================================================================
// CSR build (bucketed; consolidated finish)
// ===========================================================================
__global__ __launch_bounds__(256) void k_zero(int* __restrict__ p, int n) {
    for (int i = blockIdx.x * blockDim.x + threadIdx.x; i < n; i += gridDim.x * blockDim.x)
        p[i] = 0;
}

__global__ __launch_bounds__(256) void k_bucket_count(const int* __restrict__ rows,
                                                      int* __restrict__ bcnt, int E, int NBK) {
    __shared__ int h[NBK_MAX];
    for (int i = threadIdx.x; i < NBK; i += 256) h[i] = 0;
    __syncthreads();
    for (int e = blockIdx.x * blockDim.x + threadIdx.x; e < E; e += gridDim.x * blockDim.x)
        atomicAdd(&h[rows[e] >> SH], 1);
    __syncthreads();
    for (int i = threadIdx.x; i < NBK; i += 256) {
        int v = h[i];
        if (v) atomicAdd(&bcnt[i], v);
    }
}

// exclusive scan of bucket counts; also writes row_start[N] = E
__global__ __launch_bounds__(512) void k_scan_buckets(const int* __restrict__ bcnt,
                                                      int* __restrict__ boff,
                                                      int* __restrict__ bcur,
                                                      int* __restrict__ row_start,
                                                      int NBK, int N, int E) {
    __shared__ int sd[512];
    int t = threadIdx.x;
    int own = (t < NBK) ? bcnt[t] : 0;
    sd[t] = own;
    __syncthreads();
    for (int off = 1; off < 512; off <<= 1) {
        int add = (t >= off) ? sd[t - off] : 0;
        __syncthreads();
        sd[t] += add;
        __syncthreads();
    }
    if (t < NBK) {
        int ex = sd[t] - own;
        boff[t] = ex;
        bcur[t] = ex;
    }
    if (t == 0) {
        boff[NBK] = E;
        row_start[N] = E;
    }
}

__global__ __launch_bounds__(256) void k_pairs(const int* __restrict__ rows,
                                               const int* __restrict__ cols,
                                               int* __restrict__ bcur,
                                               unsigned* __restrict__ pairs, int E, int NBK) {
    __shared__ int h[NBK_MAX];
    int e0 = blockIdx.x * CH;
    if (e0 >= E) return;
    int e1 = min(E, e0 + CH);
    for (int i = threadIdx.x; i < NBK; i += 256) h[i] = 0;
    __syncthreads();
    for (int e = e0 + threadIdx.x; e < e1; e += 256)
        atomicAdd(&h[rows[e] >> SH], 1);
    __syncthreads();
    for (int b = threadIdx.x; b < NBK; b += 256) {
        int v = h[b];
        h[b] = v ? atomicAdd(&bcur[b], v) : 0;
    }
    __syncthreads();
    for (int e = e0 + threadIdx.x; e < e1; e += 256) {
        int r = rows[e];
        int b = r >> SH;
        int p = atomicAdd(&h[b], 1);
        pairs[p] = ((unsigned)(r & (BROWS - 1)) << 24) | (unsigned)cols[e];
    }
}

// per-bucket: row histogram -> local exclusive scan -> row_start & dr ->
// place cols into csr (cursors in LDS). Buckets are contiguous row ranges,
// so row_start[r] = boff[b] + local_scan is the GLOBAL csr offset.
__global__ __launch_bounds__(256) void k_bucket_finish(const unsigned* __restrict__ pairs,
                                                       const int* __restrict__ boff,
                                                       int* __restrict__ row_start,
                                                       float* __restrict__ dr,
                                                       int* __restrict__ csr_col, int N) {
    __shared__ int h[BROWS];
    __shared__ int cur[BROWS];
    int b = blockIdx.x;
    int t = threadIdx.x;
    int lim = min(N - (b << SH), BROWS);
    h[t] = 0;
    __syncthreads();
    int p0 = boff[b], p1 = boff[b + 1];
    for (int p = p0 + t; p < p1; p += 256)
        atomicAdd(&h[pairs[p] >> 24], 1);
    __syncthreads();
    int own = h[t];
    cur[t] = own;
    __syncthreads();
    for (int off = 1; off < 256; off <<= 1) {
        int add = (t >= off) ? cur[t - off] : 0;
        __syncthreads();
        cur[t] += add;
        __syncthreads();
    }
    int rs = p0 + cur[t] - own;   // global csr offset for this row
    if (t < lim) {
        row_start[(b << SH) + t] = rs;
        dr[(b << SH) + t] = rsqrtf((float)(own + 1));
    }
    __syncthreads();
    cur[t] = rs;
    __syncthreads();
    for (int p = p0 + t; p < p1; p += 256) {
        unsigned v = pairs[p];
        int rl = v >> 24;
        int q = atomicAdd(&cur[rl], 1);
        csr_col[q] = (int)(v & 0xFFFFFF);
    }
}

// x (fp32) -> xh (fp16), pre-scaled by dr: xh[i][:] = dr[i] * x[i][:]
__global__ __launch_bounds__(256) void k_half_s(const float4* __restrict__ x4,
                                                const float* __restrict__ dr,
                                                f16x4* __restrict__ xh4, int n4) {
    for (int i = blockIdx.x * blockDim.x + threadIdx.x; i < n4; i += gridDim.x * blockDim.x) {
        float d = dr[i >> 5];   // 32 float4 per row
        float4 v = x4[i];
        xh4[i] = (f16x4){(_Float16)(v.x * d), (_Float16)(v.y * d),
                         (_Float16)(v.z * d), (_Float16)(v.w * d)};
    }
}

// ===========================================================================
// gather (prescaled fp16): out[r] = dr[r] * (xh'[r] + sum_c xh'[c])
// one wave per row; lane covers 2 consecutive halfs; 8 edges unrolled.
// Low VGPR by design -> high occupancy -> many gathers in flight.
// ===========================================================================
__global__ __launch_bounds__(256) void k_gather_s(const int* __restrict__ row_start,
                                                  const int* __restrict__ csr_col,
                                                  const _Float16* __restrict__ xh,
                                                  const float* __restrict__ dr,
                                                  float* __restrict__ out, int N) {
    int lane = threadIdx.x & 63;
    int gw = (blockIdx.x * blockDim.x + threadIdx.x) >> 6;
    int nw = (gridDim.x * blockDim.x) >> 6;
    for (int r = gw; r < N; r += nw) {
        float drr = dr[r];
        int beg = row_start[r], end = row_start[r + 1];
        const f16x2 xs = *(const f16x2*)&xh[(size_t)r * D + lane * 2];
        float a0 = (float)xs[0], a1 = (float)xs[1];
        for (int cb = beg; cb < end; cb += 64) {
            int m = end - cb;
            if (m > 64) m = 64;
            int cidx = (lane < m) ? csr_col[cb + lane] : 0;
            int j = 0;
            for (; j + 8 <= m; j += 8) {
                int c0 = __shfl(cidx, j);
                int c1 = __shfl(cidx, j + 1);
                int c2 = __shfl(cidx, j + 2);
                int c3 = __shfl(cidx, j + 3);
                int c4 = __shfl(cidx, j + 4);
                int c5 = __shfl(cidx, j + 5);
                int c6 = __shfl(cidx, j + 6);
                int c7 = __shfl(cidx, j + 7);
                f16x2 p0 = *(const f16x2*)&xh[(size_t)c0 * D + lane * 2];
                f16x2 p1 = *(const f16x2*)&xh[(size_t)c1 * D + lane * 2];
                f16x2 p2 = *(const f16x2*)&xh[(size_t)c2 * D + lane * 2];
                f16x2 p3 = *(const f16x2*)&xh[(size_t)c3 * D + lane * 2];
                f16x2 p4 = *(const f16x2*)&xh[(size_t)c4 * D + lane * 2];
                f16x2 p5 = *(const f16x2*)&xh[(size_t)c5 * D + lane * 2];
                f16x2 p6 = *(const f16x2*)&xh[(size_t)c6 * D + lane * 2];
                f16x2 p7 = *(const f16x2*)&xh[(size_t)c7 * D + lane * 2];
                a0 += (float)p0[0] + (float)p1[0] + (float)p2[0] + (float)p3[0]
                    + (float)p4[0] + (float)p5[0] + (float)p6[0] + (float)p7[0];
                a1 += (float)p0[1] + (float)p1[1] + (float)p2[1] + (float)p3[1]
                    + (float)p4[1] + (float)p5[1] + (float)p6[1] + (float)p7[1];
            }
            for (; j < m; ++j) {
                int c = __shfl(cidx, j);
                f16x2 p = *(const f16x2*)&xh[(size_t)c * D + lane * 2];
                a0 += (float)p[0];
                a1 += (float)p[1];
            }
        }
        float2 o;
        o.x = drr * a0;
        o.y = drr * a1;
        *(float2*)&out[(size_t)r * D + lane * 2] = o;
    }
}

// ===========================================================================
// projection + relu via MFMA (bf16 split), in place (proven rounds 3/5)
// ===========================================================================
__global__ __launch_bounds__(256) void k_project_mfma(const float* __restrict__ W,
                                                      float* __restrict__ out, int N) {
    __shared__ bf16x8 Bhi[CT * KS * 64];
    __shared__ bf16x8 Blo[CT * KS * 64];
    for (int f = threadIdx.x; f < CT * KS * 64; f += 256) {
        int l  = f & 63;
        int ks = (f >> 6) & 3;
        int ct = f >> 8;
        int o  = ct * 16 + (l & 15);
        int k0 = ks * 32 + ((l >> 4) * 8);
        const float* src = &W[o * D + k0];
        bf16x8 hi, lo;
#pragma unroll
        for (int i = 0; i < 8; ++i) {
            float v  = src[i];
            __bf16 h = (__bf16)v;
            hi[i] = h;
            lo[i] = (__bf16)(v - (float)h);
        }
        Bhi[f] = hi;
        Blo[f] = lo;
    }
    __syncthreads();

    int lane = threadIdx.x & 63;
    int wib  = threadIdx.x >> 6;
    int gw   = blockIdx.x * 4 + wib;
    int nw   = gridDim.x * 4;
    int nt   = N >> 4;
    int arow  = lane & 15;
    int kbase = (lane >> 4) * 8;

    for (int t = gw; t < nt; t += nw) {
        int row = t * 16 + arow;
        const float* arp = &out[(size_t)row * D + kbase];
        bf16x8 Ahi[KS], Alo[KS];
#pragma unroll
        for (int ks = 0; ks < KS; ++ks) {
            float4 v0 = *(const float4*)&arp[ks * 32];
            float4 v1 = *(const float4*)&arp[ks * 32 + 4];
            float va[8] = {v0.x, v0.y, v0.z, v0.w, v1.x, v1.y, v1.z, v1.w};
            bf16x8 hi, lo;
#pragma unroll
            for (int i = 0; i < 8; ++i) {
                __bf16 h = (__bf16)va[i];
                hi[i] = h;
                lo[i] = (__bf16)(va[i] - (float)h);
            }
            Ahi[ks] = hi;
            Alo[ks] = lo;
        }
        f32x4 acc[CT];
#pragma unroll
        for (int ct = 0; ct < CT; ++ct) acc[ct] = (f32x4){0.f, 0.f, 0.f, 0.f};
#pragma unroll
        for (int ks = 0; ks < KS; ++ks) {
#pragma unroll
            for (int ct = 0; ct < CT; ++ct) {
                bf16x8 bh = Bhi[(ct * KS + ks) * 64 + lane];
                bf16x8 bl = Blo[(ct * KS + ks) * 64 + lane];
                acc[ct] = __builtin_amdgcn_mfma_f32_16x16x32_bf16(Ahi[ks], bh, acc[ct], 0, 0, 0);
                acc[ct] = __builtin_amdgcn_mfma_f32_16x16x32_bf16(Alo[ks], bh, acc[ct], 0, 0, 0);
                acc[ct] = __builtin_amdgcn_mfma_f32_16x16x32_bf16(Ahi[ks], bl, acc[ct], 0, 0, 0);
            }
        }
        int orow = t * 16 + (lane >> 4) * 4;
        int ocol = lane & 15;
#pragma unroll
        for (int ct = 0; ct < CT; ++ct) {
#pragma unroll
            for (int reg = 0; reg < 4; ++reg) {
                out[(size_t)(orow + reg) * D + ct * 16 + ocol] = fmaxf(acc[ct][reg], 0.f);
            }
        }
    }
}

// ===========================================================================
// mid-tier fallback: fp32 gather (unscaled x, needs dr[c])
// ===========================================================================
__global__ __launch_bounds__(256) void k_gather(const int* __restrict__ row_start,
                                                const int* __restrict__ csr_col,
                                                const float* __restrict__ x,
                                                const float* __restrict__ dr,
                                                float* __restrict__ out, int N) {
    int lane = threadIdx.x & 63;
    int gw = (blockIdx.x * blockDim.x + threadIdx.x) >> 6;
    int nw = (gridDim.x * blockDim.x) >> 6;
    for (int r = gw; r < N; r += nw) {
        float drr = dr[r];
        int beg = row_start[r], end = row_start[r + 1];
        const float2 xs = *(const float2*)&x[(size_t)r * D + lane * 2];
        float s = drr * drr;
        float a0 = s * xs.x, a1 = s * xs.y;
        for (int cb = beg; cb < end; cb += 64) {
            int m = end - cb;
            if (m > 64) m = 64;
            int   cidx = (lane < m) ? csr_col[cb + lane] : 0;
            float cdr  = (lane < m) ? dr[cidx] : 0.f;
            int j = 0;
            for (; j + 4 <= m; j += 4) {
                int c0 = __shfl(cidx, j);
                int c1 = __shfl(cidx, j + 1);
                int c2 = __shfl(cidx, j + 2);
                int c3 = __shfl(cidx, j + 3);
                float v0 = drr * __shfl(cdr, j);
                float v1 = drr * __shfl(cdr, j + 1);
                float v2 = drr * __shfl(cdr, j + 2);
                float v3 = drr * __shfl(cdr, j + 3);
                const float2 p0 = *(const float2*)&x[(size_t)c0 * D + lane * 2];
                const float2 p1 = *(const float2*)&x[(size_t)c1 * D + lane * 2];
                const float2 p2 = *(const float2*)&x[(size_t)c2 * D + lane * 2];
                const float2 p3 = *(const float2*)&x[(size_t)c3 * D + lane * 2];
                a0 = fmaf(v0, p0.x, a0); a1 = fmaf(v0, p0.y, a1);
                a0 = fmaf(v1, p1.x, a0); a1 = fmaf(v1, p1.y, a1);
                a0 = fmaf(v2, p2.x, a0); a1 = fmaf(v2, p2.y, a1);
                a0 = fmaf(v3, p3.x, a0); a1 = fmaf(v3, p3.y, a1);
            }
            for (; j < m; ++j) {
                int   c = __shfl(cidx, j);
                float v = drr * __shfl(cdr, j);
                const float2 p = *(const float2*)&x[(size_t)c * D + lane * 2];
                a0 = fmaf(v, p.x, a0);
                a1 = fmaf(v, p.y, a1);
            }
        }
        float2 o;
        o.x = a0;
        o.y = a1;
        *(float2*)&out[(size_t)r * D + lane * 2] = o;
    }
}

// ===========================================================================
// last-resort fallback (atomic path)
// ===========================================================================
__global__ __launch_bounds__(256) void k_init_deg(int* __restrict__ deg, int n) {
    for (int i = blockIdx.x * blockDim.x + threadIdx.x; i < n; i += gridDim.x * blockDim.x)
        deg[i] = 1;
}
__global__ __launch_bounds__(256) void k_count_atomic(const int* __restrict__ rows,
                                                      int* __restrict__ cnt, int E) {
    for (int e = blockIdx.x * blockDim.x + threadIdx.x; e < E; e += gridDim.x * blockDim.x)
        atomicAdd(&cnt[rows[e]], 1);
}
__global__ __launch_bounds__(256) void k_rsqrt(float* __restrict__ buf, int n) {
    const int* di = (const int*)buf;
    for (int i = blockIdx.x * blockDim.x + threadIdx.x; i < n; i += gridDim.x * blockDim.x) {
        int v = di[i];
        buf[i] = rsqrtf((float)v);
    }
}
__global__ __launch_bounds__(256) void k_init_out(const float4* __restrict__ x4,
                                                  const float* __restrict__ dr,
                                                  float4* __restrict__ out4, int n4) {
    for (int i = blockIdx.x * blockDim.x + threadIdx.x; i < n4; i += gridDim.x * blockDim.x) {
        float d = dr[i >> 5];
        float s = d * d;
        float4 v = x4[i];
        out4[i] = make_float4(v.x * s, v.y * s, v.z * s, v.w * s);
    }
}
__global__ __launch_bounds__(256) void k_edges(const int* __restrict__ rows,
                                               const int* __restrict__ cols,
                                               const float* __restrict__ x,
                                               const float* __restrict__ dr,
                                               float* __restrict__ out, int E) {
    int lane = threadIdx.x & 63;
    int wib  = threadIdx.x >> 6;
    int gw   = blockIdx.x * 4 + wib;
    int nw   = gridDim.x * 4;
    for (int e = gw; e < E; e += nw) {
        int r = rows[e];
        int c = cols[e];
        float val = dr[r] * dr[c];
        const float2 xv = *(const float2*)&x[(size_t)c * D + lane * 2];
        float* po = &out[(size_t)r * D + lane * 2];
        unsafeAtomicAdd(po,     val * xv.x);
        unsafeAtomicAdd(po + 1, val * xv.y);
    }
}

// ===========================================================================
extern "C" void kernel_launch(void* const* d_in, const int* in_sizes, int n_in,
                              void* d_out, int out_size, void* d_ws, size_t ws_size,
                              hipStream_t stream) {
    const float* x   = (const float*)d_in[0];
    const int*   idx = (const int*)d_in[1];
    const float* W   = (const float*)d_in[2];
    float*       out = (float*)d_out;

    int N = in_sizes[0] / D;   // 100000
    int E = in_sizes[1] / 2;   // 1.6M
    const int* rows = idx;
    const int* cols = idx + E;

    int NBK = (N + BROWS - 1) >> SH;   // 391

    // workspace layout in 4B words
    size_t off = 0;
    size_t o_pairs = off;  off += (size_t)E;
    size_t o_csr   = off;  off += (size_t)E;
    size_t o_rs    = off;  off += (size_t)N + 1;
    size_t o_dr    = off;  off += (size_t)N;
    size_t o_bcnt  = off;  off += (size_t)NBK;
    size_t o_boff  = off;  off += (size_t)NBK + 1;
    size_t o_bcur  = off;  off += (size_t)NBK;
    off = (off + 3) & ~(size_t)3;      // 16B align
    size_t need_mid = off * 4;
    size_t o_xh    = off;  off += ((size_t)N * D) / 2;   // halves = words/2
    size_t need_full = off * 4;

    int* wsw = (int*)d_ws;
    bool shape_ok = (NBK <= NBK_MAX) && ((N & 15) == 0) && (N < (1 << 24));

    if (shape_ok && ws_size >= need_mid) {
        unsigned* pairs     = (unsigned*)(wsw + o_pairs);
        int*      csr_col   = wsw + o_csr;
        int*      row_start = wsw + o_rs;
        float*    dr        = (float*)(wsw + o_dr);
        int*      bcnt      = wsw + o_bcnt;
        int*      boff      = wsw + o_boff;
        int*      bcur      = wsw + o_bcur;

        // CSR build (bucketed, consolidated)
        k_zero<<<(NBK + 255) / 256, 256, 0, stream>>>(bcnt, NBK);
        k_bucket_count<<<512, 256, 0, stream>>>(rows, bcnt, E, NBK);
        k_scan_buckets<<<1, 512, 0, stream>>>(bcnt, boff, bcur, row_start, NBK, N, E);
        k_pairs<<<(E + CH - 1) / CH, 256, 0, stream>>>(rows, cols, bcur, pairs, E, NBK);
        k_bucket_finish<<<NBK, 256, 0, stream>>>(pairs, boff, row_start, dr, csr_col, N);

        if (ws_size >= need_full) {
            _Float16* xh = (_Float16*)(wsw + o_xh);
            k_half_s<<<2048, 256, 0, stream>>>((const float4*)x, dr, (f16x4*)xh, N * (D / 4));
            k_gather_s<<<4096, 256, 0, stream>>>(row_start, csr_col, xh, dr, out, N);
        } else {
            k_gather<<<4096, 256, 0, stream>>>(row_start, csr_col, x, dr, out, N);
        }
        int nt = N >> 4;
        k_project_mfma<<<(nt + 3) / 4, 256, 0, stream>>>(W, out, N);
    } else {
        int*   deg = (int*)d_ws;
        float* dr  = (float*)d_ws;
        k_init_deg<<<(N + 255) / 256, 256, 0, stream>>>(deg, N);
        k_count_atomic<<<2048, 256, 0, stream>>>(rows, deg, E);
        k_rsqrt<<<(N + 255) / 256, 256, 0, stream>>>(dr, N);
        int n4 = N * (D / 4);
        k_init_out<<<4096, 256, 0, stream>>>((const float4*)x, dr, (float4*)out, n4);
        k_edges<<<4096, 256, 0, stream>>>(rows, cols, x, dr, out, E);
        int nt = N >> 4;
        k_project_mfma<<<(nt + 3) / 4, 256, 0, stream>>>(W, out, N);
    }
}